// Round 1
// baseline (20425.151 us; speedup 1.0000x reference)
//
#include <hip/hip_runtime.h>

// ---- workspace layout (float-element offsets), total ~84.4 MB ----
// hbuf   : f32 [2][32][1024]   ping-pong hidden state (256 KB)
// cstate : f32 [32][1024]      cell state             (128 KB)
// bar    : int[4096]           barrier region (128 KB reserved):
//            leaf counters : bar[l*64], l=0..15   (256 B apart)
//            root counter  : bar[1024]
//            release slots : bar[2048 + l*64], l=0..15
// xpc    : f32 [1024][4096]    x@W chunk (32 steps)   (16 MB)
// states : f32 [16384][1024]   all h_t, row = t*32+b  (64 MB)
#define OFF_H      0ull
#define OFF_C      65536ull
#define OFF_BAR    98304ull
#define OFF_XPC    131072ull
#define OFF_STATES 4325376ull

#define BAR_ROOT   1024
#define BAR_REL    2048

static __device__ inline float sigmoidf_(float x) { return 1.f / (1.f + __expf(-x)); }
static __device__ inline float tanhf_(float x) { return 1.f - 2.f / (1.f + __expf(2.f * x)); }

// ---------------------------------------------------------------------------
// init: zero hbuf (65536 f32), cstate (32768 f32), bar (4096 ints).
// ---------------------------------------------------------------------------
__global__ __launch_bounds__(256) void k_init(float* hb, float* cs, int* bar) {
    int i = blockIdx.x * 256 + threadIdx.x;
    hb[i] = 0.f;
    if (i < 32768) cs[i] = 0.f;
    if (i < 4096) bar[i] = 0;
}

// ---------------------------------------------------------------------------
// gemm0 (one 32-step chunk): xpc[Rl][4096] = x[b][t0+(Rl>>5)][:] @ [Wi|Wf|Wg|Wc] + b
// (unchanged from green round 9)
// ---------------------------------------------------------------------------
__global__ __launch_bounds__(256) void k_gemm0(
    const float* __restrict__ x,
    const float* __restrict__ Wi, const float* __restrict__ Wf,
    const float* __restrict__ Wg, const float* __restrict__ Wc,
    const float* __restrict__ bi, const float* __restrict__ bfv,
    const float* __restrict__ bg, const float* __restrict__ bc,
    float* __restrict__ xpc, int t0)
{
    __shared__ float Ash[16 * 128];
    __shared__ float Bsh[16 * 128];
    int tid = threadIdx.x;
    int bm = blockIdx.x >> 5, bn = blockIdx.x & 31;
    int r0 = bm * 128, n0 = bn * 128;
    int gate = bn >> 3;
    int nloc = (bn & 7) * 128;
    const float* W; const float* bias;
    if (gate == 0)      { W = Wi; bias = bi; }
    else if (gate == 1) { W = Wf; bias = bfv; }
    else if (gate == 2) { W = Wg; bias = bg; }
    else                { W = Wc; bias = bc; }

    int mg = tid >> 4, ng = tid & 15;
    int m0 = mg * 8, n0l = ng * 8;
    int sm = tid >> 1, skh = (tid & 1) * 8;
    int sk = tid >> 4, snof = (tid & 15) * 8;
    int Ra = r0 + sm;
    const float* aptr = x + (size_t)(Ra & 31) * 524288
                          + (size_t)(t0 + (Ra >> 5)) * 1024 + skh;

    float acc[8][8];
    for (int i = 0; i < 8; i++)
        for (int j = 0; j < 8; j++) acc[i][j] = 0.f;

    for (int k0 = 0; k0 < 1024; k0 += 16) {
        float4 av0 = *(const float4*)(aptr + k0);
        float4 av1 = *(const float4*)(aptr + k0 + 4);
        float4 bv0 = *(const float4*)(W + (size_t)(k0 + sk) * 1024 + nloc + snof);
        float4 bv1 = *(const float4*)(W + (size_t)(k0 + sk) * 1024 + nloc + snof + 4);
        Ash[(skh + 0) * 128 + sm] = av0.x;
        Ash[(skh + 1) * 128 + sm] = av0.y;
        Ash[(skh + 2) * 128 + sm] = av0.z;
        Ash[(skh + 3) * 128 + sm] = av0.w;
        Ash[(skh + 4) * 128 + sm] = av1.x;
        Ash[(skh + 5) * 128 + sm] = av1.y;
        Ash[(skh + 6) * 128 + sm] = av1.z;
        Ash[(skh + 7) * 128 + sm] = av1.w;
        *(float4*)&Bsh[sk * 128 + snof] = bv0;
        *(float4*)&Bsh[sk * 128 + snof + 4] = bv1;
        __syncthreads();
#pragma unroll
        for (int k = 0; k < 16; k++) {
            float4 a0 = *(const float4*)&Ash[k * 128 + m0];
            float4 a1 = *(const float4*)&Ash[k * 128 + m0 + 4];
            float4 b0 = *(const float4*)&Bsh[k * 128 + n0l];
            float4 b1 = *(const float4*)&Bsh[k * 128 + n0l + 4];
            float aa[8], bb[8];
            aa[0] = a0.x; aa[1] = a0.y; aa[2] = a0.z; aa[3] = a0.w;
            aa[4] = a1.x; aa[5] = a1.y; aa[6] = a1.z; aa[7] = a1.w;
            bb[0] = b0.x; bb[1] = b0.y; bb[2] = b0.z; bb[3] = b0.w;
            bb[4] = b1.x; bb[5] = b1.y; bb[6] = b1.z; bb[7] = b1.w;
#pragma unroll
            for (int i = 0; i < 8; i++)
#pragma unroll
                for (int j = 0; j < 8; j++)
                    acc[i][j] = __builtin_fmaf(aa[i], bb[j], acc[i][j]);
        }
        __syncthreads();
    }
    float fbs[8];
#pragma unroll
    for (int j = 0; j < 8; j++) fbs[j] = bias[nloc + n0l + j];
    for (int i = 0; i < 8; i++) {
        size_t rowoff = (size_t)(r0 + m0 + i) * 4096 + n0 + n0l;
#pragma unroll
        for (int j = 0; j < 8; j++)
            xpc[rowoff + j] = acc[i][j] + fbs[j];
    }
}

// ---------------------------------------------------------------------------
// k_scan32: 32 LSTM steps in ONE persistent launch. 256 blocks x 256 thr,
// 1 block/CU (all co-resident). Block owns 4 h-cols (col0=bid*4) x 4 gates
// = 16 z-cols. Thread (ku=tid>>2, cg=tid&3) holds U_cg[k=ku*16..+16][4 cols]
// in 16 float4 REGISTERS — zero U traffic in the step loop.
// Per step: 8 passes over 4 batches: stage h(t) slice to LDS, 256 FMA/thread,
// k-reduce 64 partials in LDS, 16 owner threads do gate math (c-state in LDS,
// persists across the 32 steps; saved to global at launch end).
//
// Grid barrier (REWORKED): 2-level tree on well-separated cache lines.
//   - 16 leaf arrival counters (bar[l*64], 256 B apart), leaf = blockIdx & 15;
//     16 blocks/leaf -> only 16 serialized RMWs per line, leaves in parallel.
//   - leaf completer bumps root (bar[1024]); root completer publishes
//     release = t+1 to 16 per-leaf release slots (bar[2048 + l*64]).
//   - pollers use relaxed agent-scope atomic LOADs (no RMW traffic on the
//     arrival lines) + s_sleep backoff.
// Counters are monotone (gen = global t), continuous across the 16 launches.
// ---------------------------------------------------------------------------
__global__ __launch_bounds__(256, 1) void k_scan32(
    const float* __restrict__ Ui, const float* __restrict__ Uf,
    const float* __restrict__ Ug, const float* __restrict__ Uc,
    const float* __restrict__ xpc,
    float* hbuf, float* cstate, float* states, int* bar, int t0)
{
    __shared__ float hsh[4 * 1024];    // 16 KB  [bb(4)][k(1024)]
    __shared__ float zbuf[64 * 68];    // 17.4 KB [ku][bgc(64) pad->68]
    __shared__ float zfin[64];         // [bb*16 + g*4 + c]
    __shared__ float csh[16 * 8];      // c-state: [owner(16)][pass(8)]
    int tid = threadIdx.x;
    int col0 = blockIdx.x * 4;
    int ku = tid >> 2, cg = tid & 3;
    const float* Bu;
    if (cg == 0) Bu = Ui; else if (cg == 1) Bu = Uf;
    else if (cg == 2) Bu = Ug; else Bu = Uc;

    // persistent U slice in registers: ur[kk] = U[ku*16+kk][col0..col0+3]
    float4 ur[16];
#pragma unroll
    for (int kk = 0; kk < 16; kk++)
        ur[kk] = *(const float4*)(Bu + (size_t)(ku * 16 + kk) * 1024 + col0);

    int ob = tid >> 2, oc = tid & 3;   // owner roles (tid < 16)
    if (tid < 16) {
        for (int p = 0; p < 8; p++)
            csh[tid * 8 + p] = cstate[(size_t)(p * 4 + ob) * 1024 + col0 + oc];
    }
    __syncthreads();

    int leaf = blockIdx.x & 15;
    int* leafctr = &bar[leaf * 64];
    int* relslot = &bar[BAR_REL + leaf * 64];

    for (int tt = 0; tt < 32; tt++) {
        int t = t0 + tt;
        const float* hb = hbuf + (size_t)(t & 1) * 32768;
        float* hn = hbuf + (size_t)((t + 1) & 1) * 32768;

        for (int p = 0; p < 8; p++) {
            // owners: fetch xp for this pass early (hidden behind stage+compute)
            float xg0 = 0.f, xg1 = 0.f, xg2 = 0.f, xg3 = 0.f;
            if (tid < 16) {
                const float* xr = xpc + (size_t)(tt * 32 + p * 4 + ob) * 4096 + col0 + oc;
                xg0 = xr[0];
                xg1 = xr[1024];
                xg2 = xr[2048];
                xg3 = xr[3072];
            }
            // stage h(t) for batches p*4..p*4+3: 4096 f32, 4 float4/thread
#pragma unroll
            for (int q = 0; q < 4; q++) {
                int f = tid + q * 256;
                int r = f >> 8, k4 = f & 255;
                *(float4*)&hsh[r * 1024 + k4 * 4] =
                    *(const float4*)(hb + (size_t)(p * 4 + r) * 1024 + k4 * 4);
            }
            __syncthreads();

            float acc[4][4];
            for (int b = 0; b < 4; b++)
                for (int c = 0; c < 4; c++) acc[b][c] = 0.f;
#pragma unroll
            for (int b = 0; b < 4; b++) {
#pragma unroll
                for (int k4 = 0; k4 < 4; k4++) {
                    float4 hv = *(const float4*)&hsh[b * 1024 + ku * 16 + k4 * 4];
                    float4 u0 = ur[k4 * 4 + 0];
                    float4 u1 = ur[k4 * 4 + 1];
                    float4 u2 = ur[k4 * 4 + 2];
                    float4 u3 = ur[k4 * 4 + 3];
                    acc[b][0] = __builtin_fmaf(hv.x, u0.x, acc[b][0]);
                    acc[b][1] = __builtin_fmaf(hv.x, u0.y, acc[b][1]);
                    acc[b][2] = __builtin_fmaf(hv.x, u0.z, acc[b][2]);
                    acc[b][3] = __builtin_fmaf(hv.x, u0.w, acc[b][3]);
                    acc[b][0] = __builtin_fmaf(hv.y, u1.x, acc[b][0]);
                    acc[b][1] = __builtin_fmaf(hv.y, u1.y, acc[b][1]);
                    acc[b][2] = __builtin_fmaf(hv.y, u1.z, acc[b][2]);
                    acc[b][3] = __builtin_fmaf(hv.y, u1.w, acc[b][3]);
                    acc[b][0] = __builtin_fmaf(hv.z, u2.x, acc[b][0]);
                    acc[b][1] = __builtin_fmaf(hv.z, u2.y, acc[b][1]);
                    acc[b][2] = __builtin_fmaf(hv.z, u2.z, acc[b][2]);
                    acc[b][3] = __builtin_fmaf(hv.z, u2.w, acc[b][3]);
                    acc[b][0] = __builtin_fmaf(hv.w, u3.x, acc[b][0]);
                    acc[b][1] = __builtin_fmaf(hv.w, u3.y, acc[b][1]);
                    acc[b][2] = __builtin_fmaf(hv.w, u3.z, acc[b][2]);
                    acc[b][3] = __builtin_fmaf(hv.w, u3.w, acc[b][3]);
                }
            }
            // dump partials: zbuf[ku][b*16 + cg*4 + c]
#pragma unroll
            for (int b = 0; b < 4; b++) {
                float4 v;
                v.x = acc[b][0]; v.y = acc[b][1]; v.z = acc[b][2]; v.w = acc[b][3];
                *(float4*)&zbuf[ku * 68 + b * 16 + cg * 4] = v;
            }
            __syncthreads();

            // k-reduction: 64 threads, one (b,g,c) each
            if (tid < 64) {
                float s = 0.f;
                for (int u = 0; u < 64; u++) s += zbuf[u * 68 + tid];
                zfin[tid] = s;
            }
            __syncthreads();

            // gate math: 16 owners, one (b=p*4+ob, col=col0+oc) each
            if (tid < 16) {
                int b = p * 4 + ob;
                float zi = zfin[ob * 16 + 0 * 4 + oc] + xg0;
                float zf = zfin[ob * 16 + 1 * 4 + oc] + xg1;
                float zg = zfin[ob * 16 + 2 * 4 + oc] + xg2;
                float zc = zfin[ob * 16 + 3 * 4 + oc] + xg3;
                float ig = sigmoidf_(zi);
                float fg = sigmoidf_(zf);
                float gg = sigmoidf_(zg);   // reference applies sigmoid to g
                float ct = tanhf_(zc);
                float cv = fg * csh[tid * 8 + p] + ig * ct;
                csh[tid * 8 + p] = cv;
                float hv = gg * tanhf_(cv);
                hn[(size_t)b * 1024 + col0 + oc] = hv;
                states[((size_t)t * 32 + b) * 1024 + col0 + oc] = hv;
            }
            __syncthreads();   // hsh/zbuf/zfin reuse next pass
        }

        // ---- grid barrier: publish h(t+1), tree-arrive, load-poll release ----
        if (tid == 0) {
            __threadfence();                       // release h writes device-wide
            int a = atomicAdd(leafctr, 1) + 1;     // leaf arrivals, monotone
            if (a == 16 * (t + 1)) {               // leaf complete for step t
                __threadfence();
                int r = atomicAdd(&bar[BAR_ROOT], 1) + 1;
                if (r == 16 * (t + 1)) {           // all 16 leaves complete
                    __threadfence();
#pragma unroll
                    for (int l = 0; l < 16; l++)
                        __hip_atomic_store(&bar[BAR_REL + l * 64], t + 1,
                                           __ATOMIC_RELAXED, __HIP_MEMORY_SCOPE_AGENT);
                }
            }
            // poll own release slot: plain agent-scope loads, no RMW traffic
            while (__hip_atomic_load(relslot, __ATOMIC_RELAXED,
                                     __HIP_MEMORY_SCOPE_AGENT) <= t) {
                __builtin_amdgcn_s_sleep(8);       // ~512 cyc backoff
            }
        }
        __syncthreads();
        __threadfence();                           // acquire remote h before next read
    }

    // persist c-state for the next chunk launch
    if (tid < 16) {
        for (int p = 0; p < 8; p++)
            cstate[(size_t)(p * 4 + ob) * 1024 + col0 + oc] = csh[tid * 8 + p];
    }
}

// ---------------------------------------------------------------------------
// gemm1: out[b][t][:] = relu(states[t*32+b][:] @ Wo + bo)  (unchanged, green)
// ---------------------------------------------------------------------------
__global__ __launch_bounds__(256) void k_gemm1(
    const float* __restrict__ A, const float* __restrict__ Wo,
    const float* __restrict__ bo, float* __restrict__ outp)
{
    __shared__ float Ash[16 * 128];
    __shared__ float Bsh[16 * 128];
    int tid = threadIdx.x;
    int bm = blockIdx.x >> 3, bn = blockIdx.x & 7;
    int r0 = bm * 128, n0 = bn * 128;
    int mg = tid >> 4, ng = tid & 15;
    int m0 = mg * 8, n0l = ng * 8;
    int sm = tid >> 1, skh = (tid & 1) * 8;
    int sk = tid >> 4, snof = (tid & 15) * 8;
    const float* aptr = A + (size_t)(r0 + sm) * 1024 + skh;

    float acc[8][8];
    for (int i = 0; i < 8; i++)
        for (int j = 0; j < 8; j++) acc[i][j] = 0.f;

    for (int k0 = 0; k0 < 1024; k0 += 16) {
        float4 av0 = *(const float4*)(aptr + k0);
        float4 av1 = *(const float4*)(aptr + k0 + 4);
        float4 bv0 = *(const float4*)(Wo + (size_t)(k0 + sk) * 1024 + n0 + snof);
        float4 bv1 = *(const float4*)(Wo + (size_t)(k0 + sk) * 1024 + n0 + snof + 4);
        Ash[(skh + 0) * 128 + sm] = av0.x;
        Ash[(skh + 1) * 128 + sm] = av0.y;
        Ash[(skh + 2) * 128 + sm] = av0.z;
        Ash[(skh + 3) * 128 + sm] = av0.w;
        Ash[(skh + 4) * 128 + sm] = av1.x;
        Ash[(skh + 5) * 128 + sm] = av1.y;
        Ash[(skh + 6) * 128 + sm] = av1.z;
        Ash[(skh + 7) * 128 + sm] = av1.w;
        *(float4*)&Bsh[sk * 128 + snof] = bv0;
        *(float4*)&Bsh[sk * 128 + snof + 4] = bv1;
        __syncthreads();
#pragma unroll
        for (int k = 0; k < 16; k++) {
            float4 a0 = *(const float4*)&Ash[k * 128 + m0];
            float4 a1 = *(const float4*)&Ash[k * 128 + m0 + 4];
            float4 b0 = *(const float4*)&Bsh[k * 128 + n0l];
            float4 b1 = *(const float4*)&Bsh[k * 128 + n0l + 4];
            float aa[8], bb[8];
            aa[0] = a0.x; aa[1] = a0.y; aa[2] = a0.z; aa[3] = a0.w;
            aa[4] = a1.x; aa[5] = a1.y; aa[6] = a1.z; aa[7] = a1.w;
            bb[0] = b0.x; bb[1] = b0.y; bb[2] = b0.z; bb[3] = b0.w;
            bb[4] = b1.x; bb[5] = b1.y; bb[6] = b1.z; bb[7] = b1.w;
#pragma unroll
            for (int i = 0; i < 8; i++)
#pragma unroll
                for (int j = 0; j < 8; j++)
                    acc[i][j] = __builtin_fmaf(aa[i], bb[j], acc[i][j]);
        }
        __syncthreads();
    }
    float fbs[8];
#pragma unroll
    for (int j = 0; j < 8; j++) fbs[j] = bo[n0 + n0l + j];
    for (int i = 0; i < 8; i++) {
        int R = r0 + m0 + i;
        size_t rowoff = (size_t)(R & 31) * 524288 + (size_t)(R >> 5) * 1024 + n0 + n0l;
#pragma unroll
        for (int j = 0; j < 8; j++) {
            float v = acc[i][j] + fbs[j];
            outp[rowoff + j] = v > 0.f ? v : 0.f;
        }
    }
}

extern "C" void kernel_launch(void* const* d_in, const int* in_sizes, int n_in,
                              void* d_out, int out_size, void* d_ws, size_t ws_size,
                              hipStream_t stream)
{
    const float* x   = (const float*)d_in[0];
    const float* Wi  = (const float*)d_in[1];
    const float* Ui  = (const float*)d_in[2];
    const float* Wf  = (const float*)d_in[3];
    const float* Uf  = (const float*)d_in[4];
    const float* Wg  = (const float*)d_in[5];
    const float* Ug  = (const float*)d_in[6];
    const float* Wc  = (const float*)d_in[7];
    const float* Uc  = (const float*)d_in[8];
    const float* Wo  = (const float*)d_in[9];
    const float* bi  = (const float*)d_in[10];
    const float* bfv = (const float*)d_in[11];
    const float* bg  = (const float*)d_in[12];
    const float* bc  = (const float*)d_in[13];
    const float* bo  = (const float*)d_in[14];

    float* ws     = (float*)d_ws;
    float* hbuf   = ws + OFF_H;
    float* cstate = ws + OFF_C;
    int*   bar    = (int*)(ws + OFF_BAR);
    float* xpc    = ws + OFF_XPC;
    float* states = ws + OFF_STATES;
    float* outp   = (float*)d_out;

    k_init<<<256, 256, 0, stream>>>(hbuf, cstate, bar);
    for (int c = 0; c < 16; c++) {
        k_gemm0<<<256, 256, 0, stream>>>(x, Wi, Wf, Wg, Wc, bi, bfv, bg, bc,
                                         xpc, c * 32);
        k_scan32<<<256, 256, 0, stream>>>(Ui, Uf, Ug, Uc, xpc,
                                          hbuf, cstate, states, bar, c * 32);
    }
    k_gemm1<<<1024, 256, 0, stream>>>(states, Wo, bo, outp);
}

// Round 2
// 15229.744 us; speedup vs baseline: 1.3411x; 1.3411x over previous
//
#include <hip/hip_runtime.h>

// ---- workspace layout (float-element offsets), total ~84.4 MB ----
// hbuf   : f32 [2][32][1024]   ping-pong hidden state (256 KB)
// cstate : f32 [32][1024]      cell state             (128 KB)
// bar    : int[4096]           barrier region (128 KB reserved):
//            leaf counters : bar[l*64], l=0..15   (256 B apart)
//            root counter  : bar[1024]
//            release slots : bar[2048 + l*64], l=0..15
// xpc    : f32 [1024][4096]    x@W chunk (32 steps)   (16 MB)
// states : f32 [16384][1024]   all h_t, row = t*32+b  (64 MB)
#define OFF_H      0ull
#define OFF_C      65536ull
#define OFF_BAR    98304ull
#define OFF_XPC    131072ull
#define OFF_STATES 4325376ull

#define BAR_ROOT   1024
#define BAR_REL    2048

static __device__ inline float sigmoidf_(float x) { return 1.f / (1.f + __expf(-x)); }
static __device__ inline float tanhf_(float x) { return 1.f - 2.f / (1.f + __expf(2.f * x)); }

// ---------------------------------------------------------------------------
// init: zero hbuf (65536 f32), cstate (32768 f32), bar (4096 ints).
// ---------------------------------------------------------------------------
__global__ __launch_bounds__(256) void k_init(float* hb, float* cs, int* bar) {
    int i = blockIdx.x * 256 + threadIdx.x;
    hb[i] = 0.f;
    if (i < 32768) cs[i] = 0.f;
    if (i < 4096) bar[i] = 0;
}

// ---------------------------------------------------------------------------
// gemm0 (one 32-step chunk): xpc[Rl][4096] = x[b][t0+(Rl>>5)][:] @ [Wi|Wf|Wg|Wc] + b
// (unchanged, green)
// ---------------------------------------------------------------------------
__global__ __launch_bounds__(256) void k_gemm0(
    const float* __restrict__ x,
    const float* __restrict__ Wi, const float* __restrict__ Wf,
    const float* __restrict__ Wg, const float* __restrict__ Wc,
    const float* __restrict__ bi, const float* __restrict__ bfv,
    const float* __restrict__ bg, const float* __restrict__ bc,
    float* __restrict__ xpc, int t0)
{
    __shared__ float Ash[16 * 128];
    __shared__ float Bsh[16 * 128];
    int tid = threadIdx.x;
    int bm = blockIdx.x >> 5, bn = blockIdx.x & 31;
    int r0 = bm * 128, n0 = bn * 128;
    int gate = bn >> 3;
    int nloc = (bn & 7) * 128;
    const float* W; const float* bias;
    if (gate == 0)      { W = Wi; bias = bi; }
    else if (gate == 1) { W = Wf; bias = bfv; }
    else if (gate == 2) { W = Wg; bias = bg; }
    else                { W = Wc; bias = bc; }

    int mg = tid >> 4, ng = tid & 15;
    int m0 = mg * 8, n0l = ng * 8;
    int sm = tid >> 1, skh = (tid & 1) * 8;
    int sk = tid >> 4, snof = (tid & 15) * 8;
    int Ra = r0 + sm;
    const float* aptr = x + (size_t)(Ra & 31) * 524288
                          + (size_t)(t0 + (Ra >> 5)) * 1024 + skh;

    float acc[8][8];
    for (int i = 0; i < 8; i++)
        for (int j = 0; j < 8; j++) acc[i][j] = 0.f;

    for (int k0 = 0; k0 < 1024; k0 += 16) {
        float4 av0 = *(const float4*)(aptr + k0);
        float4 av1 = *(const float4*)(aptr + k0 + 4);
        float4 bv0 = *(const float4*)(W + (size_t)(k0 + sk) * 1024 + nloc + snof);
        float4 bv1 = *(const float4*)(W + (size_t)(k0 + sk) * 1024 + nloc + snof + 4);
        Ash[(skh + 0) * 128 + sm] = av0.x;
        Ash[(skh + 1) * 128 + sm] = av0.y;
        Ash[(skh + 2) * 128 + sm] = av0.z;
        Ash[(skh + 3) * 128 + sm] = av0.w;
        Ash[(skh + 4) * 128 + sm] = av1.x;
        Ash[(skh + 5) * 128 + sm] = av1.y;
        Ash[(skh + 6) * 128 + sm] = av1.z;
        Ash[(skh + 7) * 128 + sm] = av1.w;
        *(float4*)&Bsh[sk * 128 + snof] = bv0;
        *(float4*)&Bsh[sk * 128 + snof + 4] = bv1;
        __syncthreads();
#pragma unroll
        for (int k = 0; k < 16; k++) {
            float4 a0 = *(const float4*)&Ash[k * 128 + m0];
            float4 a1 = *(const float4*)&Ash[k * 128 + m0 + 4];
            float4 b0 = *(const float4*)&Bsh[k * 128 + n0l];
            float4 b1 = *(const float4*)&Bsh[k * 128 + n0l + 4];
            float aa[8], bb[8];
            aa[0] = a0.x; aa[1] = a0.y; aa[2] = a0.z; aa[3] = a0.w;
            aa[4] = a1.x; aa[5] = a1.y; aa[6] = a1.z; aa[7] = a1.w;
            bb[0] = b0.x; bb[1] = b0.y; bb[2] = b0.z; bb[3] = b0.w;
            bb[4] = b1.x; bb[5] = b1.y; bb[6] = b1.z; bb[7] = b1.w;
#pragma unroll
            for (int i = 0; i < 8; i++)
#pragma unroll
                for (int j = 0; j < 8; j++)
                    acc[i][j] = __builtin_fmaf(aa[i], bb[j], acc[i][j]);
        }
        __syncthreads();
    }
    float fbs[8];
#pragma unroll
    for (int j = 0; j < 8; j++) fbs[j] = bias[nloc + n0l + j];
    for (int i = 0; i < 8; i++) {
        size_t rowoff = (size_t)(r0 + m0 + i) * 4096 + n0 + n0l;
#pragma unroll
        for (int j = 0; j < 8; j++)
            xpc[rowoff + j] = acc[i][j] + fbs[j];
    }
}

// ---------------------------------------------------------------------------
// k_scan32: 32 LSTM steps in ONE persistent launch. 256 blocks x 256 thr,
// 1 block/CU. Block owns 4 h-cols x 4 gates. U slice in registers.
//
// COHERENCE REWORK (this round): NO __threadfence() anywhere in the step
// loop (agent fences lower to buffer_wbl2/buffer_inv = whole-L2 maintenance,
// serialized across the 32 blocks sharing each XCD's L2 — the dominant
// per-step cost per R1 counters: VALUBusy 7.7%, 4.6 MB/step HBM re-fetch).
// Instead, only the 128 h floats/block/step are made coherent:
//   - h stores  : __hip_atomic_store RELAXED/AGENT (write-through past L2;
//                 complete at LLC when vmcnt retires; __syncthreads drains
//                 vmcnt(0) before tid0 arrives at the barrier)
//   - h loads   : __hip_atomic_load RELAXED/AGENT (L2-bypassing, reads LLC)
//   - barrier   : RELAXED atomics only (RELEASE would re-emit wbl2)
// states/cstate stay plain cached stores (read only after kernel-end flush).
// All coherent ops meet at the single LLC coherence point; each completes
// before its dependent successor issues, so ordering holds without fences.
// ---------------------------------------------------------------------------
__global__ __launch_bounds__(256, 1) void k_scan32(
    const float* __restrict__ Ui, const float* __restrict__ Uf,
    const float* __restrict__ Ug, const float* __restrict__ Uc,
    const float* __restrict__ xpc,
    float* hbuf, float* cstate, float* states, int* bar, int t0)
{
    __shared__ float hsh[4 * 1024];    // 16 KB  [bb(4)][k(1024)]
    __shared__ float zbuf[64 * 68];    // 17.4 KB [ku][bgc(64) pad->68]
    __shared__ float zfin[64];         // [bb*16 + g*4 + c]
    __shared__ float csh[16 * 8];      // c-state: [owner(16)][pass(8)]
    int tid = threadIdx.x;
    int col0 = blockIdx.x * 4;
    int ku = tid >> 2, cg = tid & 3;
    const float* Bu;
    if (cg == 0) Bu = Ui; else if (cg == 1) Bu = Uf;
    else if (cg == 2) Bu = Ug; else Bu = Uc;

    // persistent U slice in registers: ur[kk] = U[ku*16+kk][col0..col0+3]
    float4 ur[16];
#pragma unroll
    for (int kk = 0; kk < 16; kk++)
        ur[kk] = *(const float4*)(Bu + (size_t)(ku * 16 + kk) * 1024 + col0);

    int ob = tid >> 2, oc = tid & 3;   // owner roles (tid < 16)
    if (tid < 16) {
        for (int p = 0; p < 8; p++)
            csh[tid * 8 + p] = cstate[(size_t)(p * 4 + ob) * 1024 + col0 + oc];
    }
    __syncthreads();

    int leaf = blockIdx.x & 15;
    int* leafctr = &bar[leaf * 64];
    int* relslot = &bar[BAR_REL + leaf * 64];

    for (int tt = 0; tt < 32; tt++) {
        int t = t0 + tt;
        const float* hb = hbuf + (size_t)(t & 1) * 32768;
        float* hn = hbuf + (size_t)((t + 1) & 1) * 32768;

        for (int p = 0; p < 8; p++) {
            // owners: fetch xp for this pass early (hidden behind stage+compute)
            float xg0 = 0.f, xg1 = 0.f, xg2 = 0.f, xg3 = 0.f;
            if (tid < 16) {
                const float* xr = xpc + (size_t)(tt * 32 + p * 4 + ob) * 4096 + col0 + oc;
                xg0 = xr[0];
                xg1 = xr[1024];
                xg2 = xr[2048];
                xg3 = xr[3072];
            }
            // stage h(t) for batches p*4..p*4+3: 4096 f32, 16 coherent dwords/thread
#pragma unroll
            for (int q = 0; q < 4; q++) {
                int f = tid + q * 256;
                int r = f >> 8, k4 = f & 255;
                const float* src = hb + (size_t)(p * 4 + r) * 1024 + k4 * 4;
                float4 hv4;
                hv4.x = __hip_atomic_load(src + 0, __ATOMIC_RELAXED, __HIP_MEMORY_SCOPE_AGENT);
                hv4.y = __hip_atomic_load(src + 1, __ATOMIC_RELAXED, __HIP_MEMORY_SCOPE_AGENT);
                hv4.z = __hip_atomic_load(src + 2, __ATOMIC_RELAXED, __HIP_MEMORY_SCOPE_AGENT);
                hv4.w = __hip_atomic_load(src + 3, __ATOMIC_RELAXED, __HIP_MEMORY_SCOPE_AGENT);
                *(float4*)&hsh[r * 1024 + k4 * 4] = hv4;
            }
            __syncthreads();

            float acc[4][4];
            for (int b = 0; b < 4; b++)
                for (int c = 0; c < 4; c++) acc[b][c] = 0.f;
#pragma unroll
            for (int b = 0; b < 4; b++) {
#pragma unroll
                for (int k4 = 0; k4 < 4; k4++) {
                    float4 hv = *(const float4*)&hsh[b * 1024 + ku * 16 + k4 * 4];
                    float4 u0 = ur[k4 * 4 + 0];
                    float4 u1 = ur[k4 * 4 + 1];
                    float4 u2 = ur[k4 * 4 + 2];
                    float4 u3 = ur[k4 * 4 + 3];
                    acc[b][0] = __builtin_fmaf(hv.x, u0.x, acc[b][0]);
                    acc[b][1] = __builtin_fmaf(hv.x, u0.y, acc[b][1]);
                    acc[b][2] = __builtin_fmaf(hv.x, u0.z, acc[b][2]);
                    acc[b][3] = __builtin_fmaf(hv.x, u0.w, acc[b][3]);
                    acc[b][0] = __builtin_fmaf(hv.y, u1.x, acc[b][0]);
                    acc[b][1] = __builtin_fmaf(hv.y, u1.y, acc[b][1]);
                    acc[b][2] = __builtin_fmaf(hv.y, u1.z, acc[b][2]);
                    acc[b][3] = __builtin_fmaf(hv.y, u1.w, acc[b][3]);
                    acc[b][0] = __builtin_fmaf(hv.z, u2.x, acc[b][0]);
                    acc[b][1] = __builtin_fmaf(hv.z, u2.y, acc[b][1]);
                    acc[b][2] = __builtin_fmaf(hv.z, u2.z, acc[b][2]);
                    acc[b][3] = __builtin_fmaf(hv.z, u2.w, acc[b][3]);
                    acc[b][0] = __builtin_fmaf(hv.w, u3.x, acc[b][0]);
                    acc[b][1] = __builtin_fmaf(hv.w, u3.y, acc[b][1]);
                    acc[b][2] = __builtin_fmaf(hv.w, u3.z, acc[b][2]);
                    acc[b][3] = __builtin_fmaf(hv.w, u3.w, acc[b][3]);
                }
            }
            // dump partials: zbuf[ku][b*16 + cg*4 + c]
#pragma unroll
            for (int b = 0; b < 4; b++) {
                float4 v;
                v.x = acc[b][0]; v.y = acc[b][1]; v.z = acc[b][2]; v.w = acc[b][3];
                *(float4*)&zbuf[ku * 68 + b * 16 + cg * 4] = v;
            }
            __syncthreads();

            // k-reduction: 64 threads, one (b,g,c) each
            if (tid < 64) {
                float s = 0.f;
                for (int u = 0; u < 64; u++) s += zbuf[u * 68 + tid];
                zfin[tid] = s;
            }
            __syncthreads();

            // gate math: 16 owners, one (b=p*4+ob, col=col0+oc) each
            if (tid < 16) {
                int b = p * 4 + ob;
                float zi = zfin[ob * 16 + 0 * 4 + oc] + xg0;
                float zf = zfin[ob * 16 + 1 * 4 + oc] + xg1;
                float zg = zfin[ob * 16 + 2 * 4 + oc] + xg2;
                float zc = zfin[ob * 16 + 3 * 4 + oc] + xg3;
                float ig = sigmoidf_(zi);
                float fg = sigmoidf_(zf);
                float gg = sigmoidf_(zg);   // reference applies sigmoid to g
                float ct = tanhf_(zc);
                float cv = fg * csh[tid * 8 + p] + ig * ct;
                csh[tid * 8 + p] = cv;
                float hv = gg * tanhf_(cv);
                // coherent write-through store: visible at LLC once vmcnt
                // retires; the pass-final __syncthreads drains vmcnt(0)
                __hip_atomic_store(&hn[(size_t)b * 1024 + col0 + oc], hv,
                                   __ATOMIC_RELAXED, __HIP_MEMORY_SCOPE_AGENT);
                states[((size_t)t * 32 + b) * 1024 + col0 + oc] = hv;
            }
            __syncthreads();   // hsh/zbuf/zfin reuse next pass; drains h stores
        }

        // ---- grid barrier: tree-arrive (RELAXED), load-poll release ----
        // h stores already at LLC (write-through + syncthreads vmcnt drain).
        if (tid == 0) {
            int a = __hip_atomic_fetch_add(leafctr, 1, __ATOMIC_RELAXED,
                                           __HIP_MEMORY_SCOPE_AGENT) + 1;
            if (a == 16 * (t + 1)) {               // leaf complete for step t
                int r = __hip_atomic_fetch_add(&bar[BAR_ROOT], 1, __ATOMIC_RELAXED,
                                               __HIP_MEMORY_SCOPE_AGENT) + 1;
                if (r == 16 * (t + 1)) {           // all 16 leaves complete
#pragma unroll
                    for (int l = 0; l < 16; l++)
                        __hip_atomic_store(&bar[BAR_REL + l * 64], t + 1,
                                           __ATOMIC_RELAXED, __HIP_MEMORY_SCOPE_AGENT);
                }
            }
            // poll own release slot: plain agent-scope loads, no RMW traffic
            while (__hip_atomic_load(relslot, __ATOMIC_RELAXED,
                                     __HIP_MEMORY_SCOPE_AGENT) <= t) {
                __builtin_amdgcn_s_sleep(2);       // ~128 cyc backoff
            }
        }
        __syncthreads();
        // no acquire fence needed: next step's h reads are L2-bypassing
    }

    // persist c-state for the next chunk launch (plain; kernel-end flush)
    if (tid < 16) {
        for (int p = 0; p < 8; p++)
            cstate[(size_t)(p * 4 + ob) * 1024 + col0 + oc] = csh[tid * 8 + p];
    }
}

// ---------------------------------------------------------------------------
// gemm1: out[b][t][:] = relu(states[t*32+b][:] @ Wo + bo)  (unchanged, green)
// ---------------------------------------------------------------------------
__global__ __launch_bounds__(256) void k_gemm1(
    const float* __restrict__ A, const float* __restrict__ Wo,
    const float* __restrict__ bo, float* __restrict__ outp)
{
    __shared__ float Ash[16 * 128];
    __shared__ float Bsh[16 * 128];
    int tid = threadIdx.x;
    int bm = blockIdx.x >> 3, bn = blockIdx.x & 7;
    int r0 = bm * 128, n0 = bn * 128;
    int mg = tid >> 4, ng = tid & 15;
    int m0 = mg * 8, n0l = ng * 8;
    int sm = tid >> 1, skh = (tid & 1) * 8;
    int sk = tid >> 4, snof = (tid & 15) * 8;
    const float* aptr = A + (size_t)(r0 + sm) * 1024 + skh;

    float acc[8][8];
    for (int i = 0; i < 8; i++)
        for (int j = 0; j < 8; j++) acc[i][j] = 0.f;

    for (int k0 = 0; k0 < 1024; k0 += 16) {
        float4 av0 = *(const float4*)(aptr + k0);
        float4 av1 = *(const float4*)(aptr + k0 + 4);
        float4 bv0 = *(const float4*)(Wo + (size_t)(k0 + sk) * 1024 + n0 + snof);
        float4 bv1 = *(const float4*)(Wo + (size_t)(k0 + sk) * 1024 + n0 + snof + 4);
        Ash[(skh + 0) * 128 + sm] = av0.x;
        Ash[(skh + 1) * 128 + sm] = av0.y;
        Ash[(skh + 2) * 128 + sm] = av0.z;
        Ash[(skh + 3) * 128 + sm] = av0.w;
        Ash[(skh + 4) * 128 + sm] = av1.x;
        Ash[(skh + 5) * 128 + sm] = av1.y;
        Ash[(skh + 6) * 128 + sm] = av1.z;
        Ash[(skh + 7) * 128 + sm] = av1.w;
        *(float4*)&Bsh[sk * 128 + snof] = bv0;
        *(float4*)&Bsh[sk * 128 + snof + 4] = bv1;
        __syncthreads();
#pragma unroll
        for (int k = 0; k < 16; k++) {
            float4 a0 = *(const float4*)&Ash[k * 128 + m0];
            float4 a1 = *(const float4*)&Ash[k * 128 + m0 + 4];
            float4 b0 = *(const float4*)&Bsh[k * 128 + n0l];
            float4 b1 = *(const float4*)&Bsh[k * 128 + n0l + 4];
            float aa[8], bb[8];
            aa[0] = a0.x; aa[1] = a0.y; aa[2] = a0.z; aa[3] = a0.w;
            aa[4] = a1.x; aa[5] = a1.y; aa[6] = a1.z; aa[7] = a1.w;
            bb[0] = b0.x; bb[1] = b0.y; bb[2] = b0.z; bb[3] = b0.w;
            bb[4] = b1.x; bb[5] = b1.y; bb[6] = b1.z; bb[7] = b1.w;
#pragma unroll
            for (int i = 0; i < 8; i++)
#pragma unroll
                for (int j = 0; j < 8; j++)
                    acc[i][j] = __builtin_fmaf(aa[i], bb[j], acc[i][j]);
        }
        __syncthreads();
    }
    float fbs[8];
#pragma unroll
    for (int j = 0; j < 8; j++) fbs[j] = bo[n0 + n0l + j];
    for (int i = 0; i < 8; i++) {
        int R = r0 + m0 + i;
        size_t rowoff = (size_t)(R & 31) * 524288 + (size_t)(R >> 5) * 1024 + n0 + n0l;
#pragma unroll
        for (int j = 0; j < 8; j++) {
            float v = acc[i][j] + fbs[j];
            outp[rowoff + j] = v > 0.f ? v : 0.f;
        }
    }
}

extern "C" void kernel_launch(void* const* d_in, const int* in_sizes, int n_in,
                              void* d_out, int out_size, void* d_ws, size_t ws_size,
                              hipStream_t stream)
{
    const float* x   = (const float*)d_in[0];
    const float* Wi  = (const float*)d_in[1];
    const float* Ui  = (const float*)d_in[2];
    const float* Wf  = (const float*)d_in[3];
    const float* Uf  = (const float*)d_in[4];
    const float* Wg  = (const float*)d_in[5];
    const float* Ug  = (const float*)d_in[6];
    const float* Wc  = (const float*)d_in[7];
    const float* Uc  = (const float*)d_in[8];
    const float* Wo  = (const float*)d_in[9];
    const float* bi  = (const float*)d_in[10];
    const float* bfv = (const float*)d_in[11];
    const float* bg  = (const float*)d_in[12];
    const float* bc  = (const float*)d_in[13];
    const float* bo  = (const float*)d_in[14];

    float* ws     = (float*)d_ws;
    float* hbuf   = ws + OFF_H;
    float* cstate = ws + OFF_C;
    int*   bar    = (int*)(ws + OFF_BAR);
    float* xpc    = ws + OFF_XPC;
    float* states = ws + OFF_STATES;
    float* outp   = (float*)d_out;

    k_init<<<256, 256, 0, stream>>>(hbuf, cstate, bar);
    for (int c = 0; c < 16; c++) {
        k_gemm0<<<256, 256, 0, stream>>>(x, Wi, Wf, Wg, Wc, bi, bfv, bg, bc,
                                         xpc, c * 32);
        k_scan32<<<256, 256, 0, stream>>>(Ui, Uf, Ug, Uc, xpc,
                                          hbuf, cstate, states, bar, c * 32);
    }
    k_gemm1<<<1024, 256, 0, stream>>>(states, Wo, bo, outp);
}